// Round 6
// baseline (218.632 us; speedup 1.0000x reference)
//
#include <hip/hip_runtime.h>

// ConvSoftArgmax2d: x (8,16,512,512) fp32 -> coords (128,2,256,256), resp (128,1,256,256)
// 3x3 window, stride 2, pad 1. Padding contributes 0 to the pooled exp-sums.
// v5: v4's ROWX float4 trick, but 2 output rows per thread (ho = 2hp, 2hp+1).
//     5 row-loads serve 2 outputs (shared input row 4hp+1 reused in-register,
//     its exp2 computed once). NO swizzle, NO shfl, NO divergent fix-ups
//     (those sank v2/v3). Same wo mapping, same store pattern as v4.

#define H  512
#define W  512
#define HO 256
#define WO 256
#define BC 128

__global__ __launch_bounds__(256) void casm_kernel(
    const float* __restrict__ x, const float* __restrict__ temp,
    float* __restrict__ out)
{
    int idx = blockIdx.x * 256 + threadIdx.x;
    int wo = idx & (WO - 1);
    int hp = (idx >> 8) & 127;        // ho pair: 2hp, 2hp+1 (block-uniform)
    int bc = idx >> 15;

    // exp(v/T) = exp2(v * log2e / T)
    float k = 1.44269504088896340736f / fmaxf(temp[0], 1e-8f);

    const float* __restrict__ xp = x + (size_t)bc * (H * W);

    bool  w0 = (wo == 0);
    int   cb = w0 ? 0 : (2 * wo - 2); // float4 base col (8B aligned)
    float mL = w0 ? 0.0f : 1.0f;      // left-column pad mask

#define EXPK(u) __builtin_amdgcn_exp2f(k * (u))
    // One float4 per row: cols cb..cb+3. Normal lanes: (L,M,R) = (.y,.z,.w).
    // wo==0 lane: base clamped to 0 -> (M,R) = (.x,.y), L masked to zero.
#define ROWX(rowptr, rs, eLo, eRo, nvo) {                    \
        float4 v = *(const float4*)((rowptr) + cb);          \
        float vL = v.y;                                      \
        float vM = w0 ? v.x : v.z;                           \
        float vR = w0 ? v.y : v.w;                           \
        float eL = mL * EXPK(vL);                            \
        float eM = EXPK(vM);                                 \
        float eR = EXPK(vR);                                 \
        rs  = eL + eM + eR;                                  \
        eLo = eL; eRo = eR;                                  \
        nvo = fmaf(eL, vL, fmaf(eM, vM, eR * vR)); }

    // rows 4hp-1 .. 4hp+3; ho0 uses {A,B,C}, ho1 uses {C,D,E} (C shared)
    const float* __restrict__ rB = xp + (size_t)(4 * hp) * W;
    float sA = 0.f, lA = 0.f, rA = 0.f, nA = 0.f;
    float sB, lB, rrB, nB, sC, lC, rC, nC, sD, lD, rD, nD, sE, lE, rE, nE;

    if (hp != 0) ROWX(rB - W, sA, lA, rA, nA);   // row 4hp-1 (block-uniform skip)
    ROWX(rB,         sB, lB, rrB, nB);           // row 4hp
    ROWX(rB + W,     sC, lC, rC,  nC);           // row 4hp+1 (shared)
    ROWX(rB + 2 * W, sD, lD, rD,  nD);           // row 4hp+2
    ROWX(rB + 3 * W, sE, lE, rE,  nE);           // row 4hp+3
#undef ROWX
#undef EXPK

    const float scale = 2.0f / 511.0f;
    int ho0 = 2 * hp;

    // ho0 = 2hp: rows A,B,C
    float den0 = sA + sB + sC + 1e-12f;
    float i0   = __builtin_amdgcn_rcpf(den0);
    float cx0  = (((rA + rrB + rC) - (lA + lB + lC)) * i0 + (float)(2 * wo)) * scale - 1.0f;
    float cy0  = ((sC - sA) * i0 + (float)(2 * ho0)) * scale - 1.0f;
    float rs0  = (nA + nB + nC) * i0;

    // ho1 = 2hp+1: rows C,D,E
    float den1 = sC + sD + sE + 1e-12f;
    float i1   = __builtin_amdgcn_rcpf(den1);
    float cx1  = (((rC + rD + rE) - (lC + lD + lE)) * i1 + (float)(2 * wo)) * scale - 1.0f;
    float cy1  = ((sE - sC) * i1 + (float)(2 * ho0 + 2)) * scale - 1.0f;
    float rs1  = (nC + nD + nE) * i1;

    size_t pix0  = (size_t)ho0 * WO + wo;
    size_t pix1  = pix0 + WO;
    size_t cbase = (size_t)bc * (2 * HO * WO);
    size_t rbase = (size_t)BC * 2 * HO * WO + (size_t)bc * HO * WO;

    out[cbase + pix0]           = cx0;           // ch0: x, ho0
    out[cbase + HO * WO + pix0] = cy0;           // ch1: y, ho0
    out[rbase + pix0]           = rs0;           // resp,  ho0
    out[cbase + pix1]           = cx1;           // ch0: x, ho1
    out[cbase + HO * WO + pix1] = cy1;           // ch1: y, ho1
    out[rbase + pix1]           = rs1;           // resp,  ho1
}

extern "C" void kernel_launch(void* const* d_in, const int* in_sizes, int n_in,
                              void* d_out, int out_size, void* d_ws, size_t ws_size,
                              hipStream_t stream) {
    const float* x    = (const float*)d_in[0];
    const float* temp = (const float*)d_in[1];
    float* out        = (float*)d_out;

    int total  = BC * (HO / 2) * WO;    // 4,194,304 threads, 2 outputs each
    int blocks = total / 256;           // 16384
    casm_kernel<<<blocks, 256, 0, stream>>>(x, temp, out);
}

// Round 7
// 214.906 us; speedup vs baseline: 1.0173x; 1.0173x over previous
//
#include <hip/hip_runtime.h>

// ConvSoftArgmax2d: x (8,16,512,512) fp32 -> coords (128,2,256,256), resp (128,1,256,256)
// 3x3 window, stride 2, pad 1. Padding contributes 0 to the pooled exp-sums.
// v6 == v4 (best measured: 214.8 µs total; v5's 2-rows/thread regressed to 218.6).
//     1 output/thread; each row's 3 columns (2wo-1, 2wo, 2wo+1) from a single
//     dword-aligned float4 at col 2wo-2 (discard .x). wo==0 lane clamps base
//     to 0 and selects .x/.y via predicated moves. No swizzle, no shfl, no
//     ds ops, no divergence. Latency/TLP-bound: max thread count wins.

#define H  512
#define W  512
#define HO 256
#define WO 256
#define BC 128

__global__ __launch_bounds__(256) void casm_kernel(
    const float* __restrict__ x, const float* __restrict__ temp,
    float* __restrict__ out)
{
    int idx = blockIdx.x * 256 + threadIdx.x;
    int wo = idx & (WO - 1);
    int ho = (idx >> 8) & (HO - 1);   // block-uniform (256 threads = one wo-row)
    int bc = idx >> 16;

    // exp(v/T) = exp2(v * log2e / T)
    float k = 1.44269504088896340736f / fmaxf(temp[0], 1e-8f);

    const float* __restrict__ xp = x + (size_t)bc * (H * W);
    int r0 = 2 * ho - 1;              // only ho==0 gives r0 < 0 (block-uniform)

    bool  w0 = (wo == 0);
    int   cb = w0 ? 0 : (2 * wo - 2); // float4 base col (dword/8B aligned)
    float mL = w0 ? 0.0f : 1.0f;      // left-column pad mask

#define EXPK(u) __builtin_amdgcn_exp2f(k * (u))
    // One float4 per row: cols cb..cb+3. Normal lanes: (L,M,R) = (.y,.z,.w).
    // wo==0 lane: base clamped to 0 -> (M,R) = (.x,.y), L masked to zero.
#define ROWX(rowptr, rs) {                                   \
        float4 v = *(const float4*)((rowptr) + cb);          \
        float vL = v.y;                                      \
        float vM = w0 ? v.x : v.z;                           \
        float vR = w0 ? v.y : v.w;                           \
        float eL = mL * EXPK(vL);                            \
        float eM = EXPK(vM);                                 \
        float eR = EXPK(vR);                                 \
        rs = eL + eM + eR;                                   \
        colL += eL;  colR += eR;                             \
        numv = fmaf(eL, vL, fmaf(eM, vM, fmaf(eR, vR, numv))); }

    float s0 = 0.f, s1, s2;           // per-row exp sums
    float colL = 0.f, colR = 0.f, numv = 0.f;

    if (r0 >= 0) ROWX(xp + r0 * W, s0);        // row 0 (block-uniform skip)
    ROWX(xp + (r0 + 1) * W, s1);               // row 1 (always in bounds)
    ROWX(xp + (r0 + 2) * W, s2);               // row 2 (always in bounds)
#undef ROWX
#undef EXPK

    float den = s0 + s1 + s2 + 1e-12f;
    float inv_den = __builtin_amdgcn_rcpf(den);
    const float scale = 2.0f / 511.0f;
    float cx   = ((colR - colL) * inv_den + (float)(2 * wo)) * scale - 1.0f;
    float cy   = ((s2 - s0)    * inv_den + (float)(2 * ho)) * scale - 1.0f;
    float resp = numv * inv_den;

    size_t pix   = (size_t)ho * WO + wo;
    size_t cbase = (size_t)bc * (2 * HO * WO) + pix;
    out[cbase]           = cx;                                     // channel 0: x
    out[cbase + HO * WO] = cy;                                     // channel 1: y
    out[(size_t)BC * 2 * HO * WO + (size_t)bc * HO * WO + pix] = resp;
}

extern "C" void kernel_launch(void* const* d_in, const int* in_sizes, int n_in,
                              void* d_out, int out_size, void* d_ws, size_t ws_size,
                              hipStream_t stream) {
    const float* x    = (const float*)d_in[0];
    const float* temp = (const float*)d_in[1];
    float* out        = (float*)d_out;

    int total  = BC * HO * WO;          // 8,388,608 output pixels
    int blocks = total / 256;           // 32768
    casm_kernel<<<blocks, 256, 0, stream>>>(x, temp, out);
}